// Round 2
// baseline (818.099 us; speedup 1.0000x reference)
//
#include <hip/hip_runtime.h>

// Problem constants (fixed by the reference file).
constexpr int B = 16384;   // rows
constexpr int C = 10000;   // classes
constexpr int L = 20;      // labels per row
constexpr int THREADS = 256;
constexpr int BLOCKS = 2048;                    // copy-ubench-like grid
constexpr int WAVES = BLOCKS * (THREADS / 64);  // 8192 waves
constexpr int ROWS_PER_WAVE = B / WAVES;        // 2 adjacent rows per wave
constexpr int VECS = C / 4;                     // 2500 float4 per row
constexpr int WLOADS = VECS / 64;               // 39 full wave-wide loads
constexpr int WTAIL = VECS - WLOADS * 64;       // 4 remaining vec4 (lanes 0..3)

// Clang-native vector type: guarantees global_load_dwordx4 on dereference.
typedef float vfloat4 __attribute__((ext_vector_type(4)));

// R1 restructure: ONE WAVE PER ROW (was one 256-thread block per row).
// Rationale: R0's NT->plain flip was null, so the load flavor is not the
// limiter. The remaining structural differences from the 6.3 TB/s copy
// ubench were block-level coupling (__syncthreads + LDS reduce), the
// divergent tail iteration, and 16384 small blocks. This version makes
// every wave fully autonomous:
//   - 2048 blocks x 4 waves; each wave streams 2 ADJACENT rows (80 KB
//     contiguous) as 39 back-to-back dwordx4 per lane, unroll 13 ->
//     13 loads in flight per lane, no barrier anywhere.
//   - lanes 0..19 issue the scattered label-logit gathers BEFORE the row
//     stream so their latency hides under it.
//   - lse + prefix-validity combine entirely via 64-lane shuffles.
__global__ __launch_bounds__(THREADS) void row_loss_kernel(
    const float* __restrict__ logits,
    const int* __restrict__ labels,
    float* __restrict__ row_loss) {
  const int lane = threadIdx.x & 63;
  const int gw = blockIdx.x * (THREADS >> 6) + (threadIdx.x >> 6);

  #pragma unroll
  for (int rr = 0; rr < ROWS_PER_WAVE; ++rr) {
    const int b = gw * ROWS_PER_WAVE + rr;
    const float* __restrict__ rowp = logits + (size_t)b * C;
    const vfloat4* __restrict__ row = reinterpret_cast<const vfloat4*>(rowp);

    // --- early gather (lanes 0..L-1) ---
    int lab = 0;
    float g = 0.0f;
    if (lane < L) {
      lab = labels[b * L + lane];
      int safe = (lab >= 0) ? lab : 0;
      g = rowp[safe];  // cold scattered load; consumed only after the stream
    }

    // --- stream the row: 39 wave-wide dwordx4 + 4-vec tail ---
    float s0 = 0.0f, s1 = 0.0f, s2 = 0.0f, s3 = 0.0f;
    #pragma unroll 13
    for (int j = 0; j < WLOADS; ++j) {
      vfloat4 v = row[lane + j * 64];
      s0 += __expf(v.x);
      s1 += __expf(v.y);
      s2 += __expf(v.z);
      s3 += __expf(v.w);
    }
    if (lane < WTAIL) {
      vfloat4 v = row[WLOADS * 64 + lane];
      s0 += __expf(v.x);
      s1 += __expf(v.y);
      s2 += __expf(v.z);
      s3 += __expf(v.w);
    }
    float s = (s0 + s1) + (s2 + s3);

    // 64-lane butterfly: every lane ends with the full row sum.
    #pragma unroll
    for (int off = 32; off; off >>= 1) s += __shfl_xor(s, off);
    const float lse = __logf(s);

    // --- combine (within the wave; no LDS, no barrier) ---
    unsigned long long mask = __ballot((lane < L) && (lab >= 0));
    float term = 0.0f;
    if (lane < L) {
      unsigned long long need = (1ull << (lane + 1)) - 1ull;  // labels[0..lane] valid
      if ((mask & need) == need) term = lse - g;               // = -log_softmax[lab]
    }
    #pragma unroll
    for (int off = 32; off; off >>= 1) term += __shfl_xor(term, off);
    if (lane == 0) row_loss[b] = term;
  }
}

// Reduce the 16384 per-row losses to the scalar output. Single block,
// deterministic, no atomics (d_out is poisoned 0xAA, so plain store).
__global__ __launch_bounds__(256) void reduce_kernel(
    const float* __restrict__ row_loss, float* __restrict__ out) {
  const int t = threadIdx.x;
  float s = 0.0f;
  #pragma unroll 4
  for (int i = t; i < B; i += 256) s += row_loss[i];
  #pragma unroll
  for (int off = 32; off; off >>= 1) s += __shfl_xor(s, off);
  __shared__ float warp_s[4];
  const int lane = t & 63, wid = t >> 6;
  if (lane == 0) warp_s[wid] = s;
  __syncthreads();
  if (t == 0) out[0] = warp_s[0] + warp_s[1] + warp_s[2] + warp_s[3];
}

extern "C" void kernel_launch(void* const* d_in, const int* in_sizes, int n_in,
                              void* d_out, int out_size, void* d_ws, size_t ws_size,
                              hipStream_t stream) {
  const float* logits = (const float*)d_in[0];
  const int* labels = (const int*)d_in[1];
  float* row_loss = (float*)d_ws;  // B floats = 64 KB scratch
  float* out = (float*)d_out;

  row_loss_kernel<<<BLOCKS, THREADS, 0, stream>>>(logits, labels, row_loss);
  reduce_kernel<<<1, 256, 0, stream>>>(row_loss, out);
}